// Round 3
// baseline (1267.236 us; speedup 1.0000x reference)
//
#include <hip/hip_runtime.h>

#define NN 10000
#define EE 160000
#define CC 32
#define NBAS 128
#define HH 64
#define LL 3

__device__ __forceinline__ float sigmoidf_(float x) { return 1.0f / (1.0f + expf(-x)); }

// ---------------------------------------------------------------------------
__device__ __forceinline__ void edge_geom(const float* pos, int src, int dst,
                                          float& inv_r, float& u, float& pref,
                                          float& x, float& y, float& z) {
    float vx = pos[dst * 3 + 0] - pos[src * 3 + 0];
    float vy = pos[dst * 3 + 1] - pos[src * 3 + 1];
    float vz = pos[dst * 3 + 2] - pos[src * 3 + 2];
    float r2 = vx * vx + vy * vy + vz * vz + 1e-12f;
    float r = sqrtf(r2);
    inv_r = 1.0f / r;
    u = fminf(r * 0.2f, 1.0f);   // r/RC, RC=5
    const float PI = 3.14159265358979f;
    float env = 0.5f * (cosf(PI * u) + 1.0f);
    pref = env * 0.6324555320336759f * inv_r;  // sqrt(2/RC)
    x = vx * inv_r; y = vy * inv_r; z = vz * inv_r;
}

__device__ __forceinline__ void sph_all(float x, float y, float z, float* shv) {
    const float s3 = 1.7320508075688772f, s5 = 2.23606797749979f, s15 = 3.872983346207417f;
    const float c1 = 2.0916500663351885f;
    const float c2 = 10.246950765959598f;
    const float c3 = 1.6201851746019649f;
    const float c4 = 1.3228756555322954f;
    const float c5 = 5.123475382979799f;
    shv[0] = 1.0f;
    shv[1] = s3 * x; shv[2] = s3 * y; shv[3] = s3 * z;
    shv[4] = s15 * x * y;
    shv[5] = s15 * y * z;
    shv[6] = 0.5f * s5 * (3.0f * z * z - 1.0f);
    shv[7] = s15 * x * z;
    shv[8] = 0.5f * s15 * (x * x - y * y);
    shv[9]  = c1 * y * (3.0f * x * x - y * y);
    shv[10] = c2 * x * y * z;
    shv[11] = c3 * y * (5.0f * z * z - 1.0f);
    shv[12] = c4 * (5.0f * z * z * z - 3.0f * z);
    shv[13] = c3 * x * (5.0f * z * z - 1.0f);
    shv[14] = c5 * z * (x * x - y * y);
    shv[15] = c1 * x * (x * x - 3.0f * y * y);
}

// ---------------------------------------------------------------------------
// CSR build
__global__ void k_deg(const int* __restrict__ ei, int* __restrict__ deg) {
    int e = blockIdx.x * blockDim.x + threadIdx.x;
    if (e < EE) atomicAdd(&deg[ei[EE + e]], 1);
}

__global__ __launch_bounds__(256) void k_scan(const int* __restrict__ deg, int* __restrict__ rowptr) {
    __shared__ int part[256];
    const int CHUNK = 40;  // 256*40 = 10240 >= NN
    int tid = threadIdx.x;
    int s = 0;
#pragma unroll
    for (int k = 0; k < CHUNK; k++) {
        int idx = tid * CHUNK + k;
        if (idx < NN) s += deg[idx];
    }
    part[tid] = s;
    __syncthreads();
    for (int off = 1; off < 256; off <<= 1) {
        int v = (tid >= off) ? part[tid - off] : 0;
        __syncthreads();
        part[tid] += v;
        __syncthreads();
    }
    int run = (tid > 0) ? part[tid - 1] : 0;
#pragma unroll
    for (int k = 0; k < CHUNK; k++) {
        int idx = tid * CHUNK + k;
        if (idx < NN) { rowptr[idx] = run; run += deg[idx]; }
    }
    if (tid == 255) rowptr[NN] = run;  // == EE
}

__global__ void k_scatter(const int* __restrict__ ei, const int* __restrict__ rowptr,
                          int* __restrict__ cursor, int* __restrict__ csr) {
    int e = blockIdx.x * blockDim.x + threadIdx.x;
    if (e >= EE) return;
    int d = ei[EE + e];
    int slot = atomicAdd(&cursor[d], 1);
    csr[rowptr[d] + slot] = e;
}

// ---------------------------------------------------------------------------
__global__ void k_init_f(const float* __restrict__ ne, const int* __restrict__ species,
                         float* __restrict__ f, float* __restrict__ f0) {
    int idx = blockIdx.x * blockDim.x + threadIdx.x;
    if (idx >= NN * CC * 16) return;
    int m = idx & 15;
    int c = (idx >> 4) & 31;
    int n = idx >> 9;
    float v = (m == 0) ? ne[species[n] * CC + c] : 0.0f;
    f[idx] = v;
    if (m == 0) f0[n * CC + c] = v;
}

// ---------------------------------------------------------------------------
// K1 (rewritten): 64-edge tile. Phase A: geometry + sh + radial basis via
// Chebyshev recurrence (2 sinf bootstrap per 32 bases instead of 32 sinf).
// Phase B: register-tile GEMM rb(64x128) @ rw1(128x64) -> silu -> hbuf.
// Replaces the old per-lane ds_read_b32 dot (LDS-issue-bound, ~150 b32/wave).
__global__ __launch_bounds__(256) void k_edge_pre(
    const float* __restrict__ pos, const float* __restrict__ rw1, const float* __restrict__ rb1,
    const int* __restrict__ ei, float* __restrict__ hbuf, float* __restrict__ shbuf) {
    __shared__ float rw1_s[NBAS * HH];     // 32 KB  [k][h]
    __shared__ float rb_s[64 * 132];       // 33 KB  [edge][k], pad->132 (4-aligned)
    int tid = threadIdx.x;
    int ebase = blockIdx.x * 64;
    // stage rw1 (already [k][h] row-major): 8 float4 per thread, coalesced
    for (int i = tid; i < NBAS * HH / 4; i += 256)
        *(float4*)&rw1_s[i * 4] = *(const float4*)&rw1[i * 4];
    // Phase A: 4 threads per edge, each covers 32 contiguous bases
    {
        int r = tid >> 2, q = tid & 3;
        int e = ebase + r;
        int src = ei[e], dst = ei[EE + e];
        float inv_r, u, pref, x, y, z;
        edge_geom(pos, src, dst, inv_r, u, pref, x, y, z);
        float shv[16];
        sph_all(x, y, z, shv);
        float4 sv;
        sv.x = shv[q * 4 + 0]; sv.y = shv[q * 4 + 1];
        sv.z = shv[q * 4 + 2]; sv.w = shv[q * 4 + 3];
        *(float4*)&shbuf[(size_t)e * 16 + q * 4] = sv;   // coalesced
        const float PI = 3.14159265358979f;
        float th = PI * u;
        float tc = 2.0f * cosf(th);
        int n0 = 32 * q + 1;
        float sp2 = sinf(th * (float)n0);        // sin(n0*theta)
        float sp1 = sinf(th * (float)(n0 + 1));  // sin((n0+1)*theta)
        float* rp = &rb_s[r * 132 + 32 * q];
        float4 v;
        v.x = pref * sp2; v.y = pref * sp1;
#pragma unroll
        for (int j = 2; j < 32; j++) {
            float s = tc * sp1 - sp2;            // sin((n0+j)*theta)
            sp2 = sp1; sp1 = s;
            float pv = pref * s;
            int m = j & 3;
            if (m == 0) v.x = pv;
            else if (m == 1) v.y = pv;
            else if (m == 2) v.z = pv;
            else { v.w = pv; *(float4*)&rp[j - 3] = v; }
        }
    }
    __syncthreads();
    // Phase B: 64x64 tile GEMM, K=128; 4 rows x 4 cols per thread
    int col0 = (tid & 15) * 4;
    int r0 = (tid >> 4) * 4;
    float acc[4][4];
#pragma unroll
    for (int i = 0; i < 4; i++) { acc[i][0] = 0.f; acc[i][1] = 0.f; acc[i][2] = 0.f; acc[i][3] = 0.f; }
#pragma unroll 2
    for (int k0 = 0; k0 < NBAS; k0 += 4) {
        float4 w0 = *(float4*)&rw1_s[(k0 + 0) * HH + col0];
        float4 w1 = *(float4*)&rw1_s[(k0 + 1) * HH + col0];
        float4 w2 = *(float4*)&rw1_s[(k0 + 2) * HH + col0];
        float4 w3 = *(float4*)&rw1_s[(k0 + 3) * HH + col0];
#pragma unroll
        for (int i = 0; i < 4; i++) {
            float4 rv = *(float4*)&rb_s[(r0 + i) * 132 + k0];  // broadcast in 16-lane groups
            acc[i][0] += rv.x * w0.x; acc[i][1] += rv.x * w0.y; acc[i][2] += rv.x * w0.z; acc[i][3] += rv.x * w0.w;
            acc[i][0] += rv.y * w1.x; acc[i][1] += rv.y * w1.y; acc[i][2] += rv.y * w1.z; acc[i][3] += rv.y * w1.w;
            acc[i][0] += rv.z * w2.x; acc[i][1] += rv.z * w2.y; acc[i][2] += rv.z * w2.z; acc[i][3] += rv.z * w2.w;
            acc[i][0] += rv.w * w3.x; acc[i][1] += rv.w * w3.y; acc[i][2] += rv.w * w3.z; acc[i][3] += rv.w * w3.w;
        }
    }
    float4 bv = *(const float4*)&rb1[col0];
#pragma unroll
    for (int i = 0; i < 4; i++) {
        float a0 = acc[i][0] + bv.x, a1 = acc[i][1] + bv.y;
        float a2 = acc[i][2] + bv.z, a3 = acc[i][3] + bv.w;
        float4 hres;
        hres.x = a0 * sigmoidf_(a0); hres.y = a1 * sigmoidf_(a1);
        hres.z = a2 * sigmoidf_(a2); hres.w = a3 * sigmoidf_(a3);
        *(float4*)&hbuf[(size_t)(ebase + r0 + i) * HH + col0] = hres;
    }
}

// ---------------------------------------------------------------------------
// K2a (fused over layers): aw[p][o] = h[csr[p]] . rw2[:, panel*128+o] + rb2
// written in CSR order, UNSCALED (f0 scale applied in k_agg2 since it is
// layer-dependent). One h staging serves npanel panels.
__global__ __launch_bounds__(256) void k_gemm_all(
    const float* __restrict__ hbuf, const float* __restrict__ rw2,
    const float* __restrict__ rb2, const int* __restrict__ csr,
    float* __restrict__ aw, int panel0, int npanel, int ostride) {
    __shared__ float w_s[HH * 128];      // 32 KB [k][o]
    __shared__ float h_s[64][68];        // 17 KB
    int tid = threadIdx.x;
    int pbase = blockIdx.x * 64;
    {
        int r = tid >> 2, q = tid & 3;
        int e = csr[pbase + r];
        const float4* hp = (const float4*)(hbuf + (size_t)e * HH + q * 16);
        float4 v0 = hp[0], v1 = hp[1], v2 = hp[2], v3 = hp[3];
        float4* dp = (float4*)&h_s[r][q * 16];
        dp[0] = v0; dp[1] = v1; dp[2] = v2; dp[3] = v3;
    }
    int ob = (tid & 31) << 2;
    int r0 = (tid >> 5) << 3;
    for (int p = 0; p < npanel; p++) {
        int wcol = (panel0 + p) * 128;
        __syncthreads();   // h_s ready (p=0) / previous compute finished
        for (int i = tid; i < HH * 32; i += 256) {
            int j = i >> 5, o4 = (i & 31) << 2;
            *(float4*)&w_s[j * 128 + o4] = *(const float4*)&rw2[(size_t)j * 384 + wcol + o4];
        }
        __syncthreads();
        float acc[8][4];
#pragma unroll
        for (int i = 0; i < 8; i++) { acc[i][0] = 0.f; acc[i][1] = 0.f; acc[i][2] = 0.f; acc[i][3] = 0.f; }
#pragma unroll 2
        for (int k0 = 0; k0 < HH; k0 += 4) {
            float4 w0 = *(float4*)&w_s[(k0 + 0) * 128 + ob];
            float4 w1 = *(float4*)&w_s[(k0 + 1) * 128 + ob];
            float4 w2 = *(float4*)&w_s[(k0 + 2) * 128 + ob];
            float4 w3 = *(float4*)&w_s[(k0 + 3) * 128 + ob];
#pragma unroll
            for (int i = 0; i < 8; i++) {
                float4 hv = *(float4*)&h_s[r0 + i][k0];
                acc[i][0] += hv.x * w0.x; acc[i][1] += hv.x * w0.y; acc[i][2] += hv.x * w0.z; acc[i][3] += hv.x * w0.w;
                acc[i][0] += hv.y * w1.x; acc[i][1] += hv.y * w1.y; acc[i][2] += hv.y * w1.z; acc[i][3] += hv.y * w1.w;
                acc[i][0] += hv.z * w2.x; acc[i][1] += hv.z * w2.y; acc[i][2] += hv.z * w2.z; acc[i][3] += hv.z * w2.w;
                acc[i][0] += hv.w * w3.x; acc[i][1] += hv.w * w3.y; acc[i][2] += hv.w * w3.z; acc[i][3] += hv.w * w3.w;
            }
        }
        float4 bv = *(const float4*)&rb2[wcol + ob];
#pragma unroll
        for (int i = 0; i < 8; i++) {
            float4 res;
            res.x = acc[i][0] + bv.x; res.y = acc[i][1] + bv.y;
            res.z = acc[i][2] + bv.z; res.w = acc[i][3] + bv.w;
            *(float4*)&aw[(size_t)(pbase + r0 + i) * ostride + p * 128 + ob] = res;
        }
    }
}

// ---------------------------------------------------------------------------
// K2b: streaming CSR gather; applies layer-dependent f0[src] scale here
// (f0 is 1.28 MB -> L2-resident).
__global__ __launch_bounds__(256) void k_agg2(
    const float* __restrict__ aw, const float* __restrict__ shbuf,
    const float* __restrict__ f0, const int* __restrict__ ei,
    const int* __restrict__ rowptr, const int* __restrict__ csr,
    float* __restrict__ agg, int coloff, int ostride) {
    int w = threadIdx.x >> 6, lane = threadIdx.x & 63;
    int n = blockIdx.x * 4 + w;
    int c = lane & 31;
    int half = lane >> 5;
    float acc0[3] = {0.f, 0.f, 0.f};
    float acc1[7] = {0.f, 0.f, 0.f, 0.f, 0.f, 0.f, 0.f};
    int beg = rowptr[n], end = rowptr[n + 1];
    for (int k = beg; k < end; k++) {
        int e = csr[k];
        int src = ei[e];
        float fs = f0[src * CC + c];
        float a0 = aw[(size_t)k * ostride + coloff + lane] * fs;
        float a1 = aw[(size_t)k * ostride + coloff + 64 + lane] * fs;
        const float4* shp = (const float4*)(shbuf + (size_t)e * 16);
        float4 s0 = shp[0], s1 = shp[1], s2 = shp[2], s3 = shp[3];
        if (half == 0) {
            acc0[0] += a0 * s0.x;
            acc1[0] += a1 * s1.x; acc1[1] += a1 * s1.y; acc1[2] += a1 * s1.z; acc1[3] += a1 * s1.w;
            acc1[4] += a1 * s2.x;
        } else {
            acc0[0] += a0 * s0.y; acc0[1] += a0 * s0.z; acc0[2] += a0 * s0.w;
            acc1[0] += a1 * s2.y; acc1[1] += a1 * s2.z; acc1[2] += a1 * s2.w;
            acc1[3] += a1 * s3.x; acc1[4] += a1 * s3.y; acc1[5] += a1 * s3.z; acc1[6] += a1 * s3.w;
        }
    }
    int l0 = half, dl0 = 2 * l0 + 1, mo0 = l0 * l0;
    int l1 = 2 + half, dl1 = 2 * l1 + 1, mo1 = l1 * l1;
    float* ap = agg + ((size_t)n * CC + c) * 16;
#pragma unroll
    for (int m = 0; m < 3; m++)
        if (m < dl0) ap[mo0 + m] = acc0[m];
#pragma unroll
    for (int m = 0; m < 7; m++)
        if (m < dl1) ap[mo1 + m] = acc1[m];
}

// ---------------------------------------------------------------------------
// K3: per-layer node update
__global__ __launch_bounds__(256) void k_node(
    const float* __restrict__ f_cur, const float* __restrict__ agg,
    const float* __restrict__ self_w, const float* __restrict__ msg_w,
    const float* __restrict__ gate_w, float* __restrict__ f_next,
    float* __restrict__ f0_out, int t) {
    __shared__ float new_s[4][CC * 16];
    __shared__ float gate_s[4][CC];
    int w = threadIdx.x >> 6, lane = threadIdx.x & 63;
    int n = blockIdx.x * 4 + w;
    int d = lane & 31, mg = lane >> 5;
#pragma unroll
    for (int k = 0; k < 8; k++) {
        int m = mg + 2 * k;
        int l = (m == 0) ? 0 : (m < 4) ? 1 : (m < 9) ? 2 : 3;
        const float* sw = self_w + (size_t)((t * 4 + l) * CC) * CC + d;
        const float* mw = msg_w + (size_t)((t * 4 + l) * CC) * CC + d;
        const float* fp = f_cur + (size_t)n * CC * 16 + m;
        const float* ap = agg + (size_t)n * CC * 16 + m;
        float acc = 0.0f;
#pragma unroll 8
        for (int c = 0; c < CC; c++)
            acc += fp[c * 16] * sw[c * CC] + ap[c * 16] * mw[c * CC];
        new_s[w][d * 16 + m] = acc;
    }
    __syncthreads();
    if (mg == 0) {
        float g = 0.0f;
#pragma unroll 8
        for (int c = 0; c < CC; c++) g += new_s[w][c * 16 + 0] * gate_w[((size_t)t * CC + c) * CC + d];
        gate_s[w][d] = sigmoidf_(g);
    }
    __syncthreads();
#pragma unroll
    for (int k = 0; k < 8; k++) {
        int m = mg + 2 * k;
        float v = new_s[w][d * 16 + m];
        if (m == 0) v = v * sigmoidf_(v);
        else v *= gate_s[w][d];
        f_next[((size_t)n * CC + d) * 16 + m] = v;
        if (m == 0) f0_out[n * CC + d] = v;
    }
}

// ---------------------------------------------------------------------------
// K4a: node output relayout
__global__ void k_out_node(const float* __restrict__ f, float* __restrict__ out) {
    int idx = blockIdx.x * blockDim.x + threadIdx.x;
    if (idx >= NN * 512) return;
    int n = idx >> 9, q = idx & 511;
    int l, c, m;
    if (q < 32) { l = 0; c = q; m = 0; }
    else if (q < 128) { l = 1; c = (q - 32) / 3; m = (q - 32) % 3; }
    else if (q < 288) { l = 2; c = (q - 128) / 5; m = (q - 128) % 5; }
    else { l = 3; c = (q - 288) / 7; m = (q - 288) % 7; }
    out[idx] = f[((size_t)n * CC + c) * 16 + l * l + m];
}

// ---------------------------------------------------------------------------
// helper: emit one row-segment of edge output (DL = 2l+1 values per channel,
// 4 channels -> DL float4 contiguous stores). All indices compile-time.
template<int DL>
__device__ __forceinline__ void emit_edge(float* outp, const float* shp,
                                          float e0, float e1, float e2, float e3) {
    float ew[4] = {e0, e1, e2, e3};
    float buf[4 * DL];
#pragma unroll
    for (int cc = 0; cc < 4; cc++)
#pragma unroll
        for (int m = 0; m < DL; m++) buf[cc * DL + m] = ew[cc] * shp[m];
#pragma unroll
    for (int t = 0; t < DL; t++) *(float4*)&outp[t * 4] = *(float4*)&buf[t * 4];
}

// ---------------------------------------------------------------------------
// K4b (fused): edge-output GEMM + sh expansion, no eaw round-trip.
// 64 edges/block; GEMM h(64x64)@edge_w(64x128), then each thread expands its
// 8 rows x 4 cols directly: out rows stay contiguous (32-lane group writes
// one 2 KB row). LDS 54.2 KB -> 3 blocks/CU.
__global__ __launch_bounds__(256) void k_edge_out(
    const float* __restrict__ hbuf, const float* __restrict__ shbuf,
    const float* __restrict__ edge_w, const float* __restrict__ edge_b,
    const float* __restrict__ f0, const int* __restrict__ ei,
    float* __restrict__ out) {
    __shared__ float w_s[HH * 128];      // 32 KB
    __shared__ float h_s[64][68];        // 17 KB
    __shared__ float sh_s[64][16];       // 4 KB
    int tid = threadIdx.x;
    int ebase = blockIdx.x * 64;
    for (int i = tid; i < HH * 32; i += 256) {
        int j = i >> 5, o4 = (i & 31) << 2;
        *(float4*)&w_s[j * 128 + o4] = *(const float4*)&edge_w[(size_t)j * 128 + o4];
    }
    {
        int r = tid >> 2, q = tid & 3;
        int e = ebase + r;
        const float4* hp = (const float4*)(hbuf + (size_t)e * HH + q * 16);
        float4 v0 = hp[0], v1 = hp[1], v2 = hp[2], v3 = hp[3];
        float4* dp = (float4*)&h_s[r][q * 16];
        dp[0] = v0; dp[1] = v1; dp[2] = v2; dp[3] = v3;
        *(float4*)&sh_s[r][q * 4] = *(const float4*)&shbuf[(size_t)e * 16 + q * 4];
    }
    __syncthreads();
    int ob = (tid & 31) << 2;
    int r0 = (tid >> 5) << 3;
    float acc[8][4];
#pragma unroll
    for (int i = 0; i < 8; i++) { acc[i][0] = 0.f; acc[i][1] = 0.f; acc[i][2] = 0.f; acc[i][3] = 0.f; }
#pragma unroll 2
    for (int k0 = 0; k0 < HH; k0 += 4) {
        float4 w0 = *(float4*)&w_s[(k0 + 0) * 128 + ob];
        float4 w1 = *(float4*)&w_s[(k0 + 1) * 128 + ob];
        float4 w2 = *(float4*)&w_s[(k0 + 2) * 128 + ob];
        float4 w3 = *(float4*)&w_s[(k0 + 3) * 128 + ob];
#pragma unroll
        for (int i = 0; i < 8; i++) {
            float4 hv = *(float4*)&h_s[r0 + i][k0];
            acc[i][0] += hv.x * w0.x; acc[i][1] += hv.x * w0.y; acc[i][2] += hv.x * w0.z; acc[i][3] += hv.x * w0.w;
            acc[i][0] += hv.y * w1.x; acc[i][1] += hv.y * w1.y; acc[i][2] += hv.y * w1.z; acc[i][3] += hv.y * w1.w;
            acc[i][0] += hv.z * w2.x; acc[i][1] += hv.z * w2.y; acc[i][2] += hv.z * w2.z; acc[i][3] += hv.z * w2.w;
            acc[i][0] += hv.w * w3.x; acc[i][1] += hv.w * w3.y; acc[i][2] += hv.w * w3.z; acc[i][3] += hv.w * w3.w;
        }
    }
    float4 bv = *(const float4*)&edge_b[ob];
    int l = ob >> 5;              // same level for all 4 cols of this thread
    int cbase = ob & 31;
    int dl = 2 * l + 1, mo = l * l, co = 32 * l * l;
#pragma unroll
    for (int i = 0; i < 8; i++) {
        int rr = r0 + i;
        int e = ebase + rr;
        int src = ei[e], dst = ei[EE + e];   // L2-hot
        float4 g1 = *(const float4*)&f0[src * CC + cbase];
        float4 g2 = *(const float4*)&f0[dst * CC + cbase];
        float e0 = (acc[i][0] + bv.x) * (g1.x + g2.x);
        float e1 = (acc[i][1] + bv.y) * (g1.y + g2.y);
        float e2 = (acc[i][2] + bv.z) * (g1.z + g2.z);
        float e3 = (acc[i][3] + bv.w) * (g1.w + g2.w);
        float* outp = out + ((size_t)NN + e) * 512 + co + (size_t)cbase * dl;
        const float* shp = &sh_s[rr][mo];
        if (l == 0)      emit_edge<1>(outp, shp, e0, e1, e2, e3);
        else if (l == 1) emit_edge<3>(outp, shp, e0, e1, e2, e3);
        else if (l == 2) emit_edge<5>(outp, shp, e0, e1, e2, e3);
        else             emit_edge<7>(outp, shp, e0, e1, e2, e3);
    }
}

// ---------------------------------------------------------------------------
// K4b deep-fallback: recomputes h and sh from pos (only if ws too small to
// keep hbuf/shbuf out of the out-region scratch).
__global__ __launch_bounds__(256) void k_out_edge(
    const float* __restrict__ pos, const float* __restrict__ rw1, const float* __restrict__ rb1,
    const float* __restrict__ edge_w, const float* __restrict__ edge_b,
    const float* __restrict__ f0, const int* __restrict__ ei, float* __restrict__ out) {
    __shared__ float rw1_s[NBAS * HH];
    __shared__ float ew_s[HH * 128];
    __shared__ float rb_s[4][NBAS];
    __shared__ float h_s[4][HH];
    __shared__ float g_s[4][CC];
    __shared__ float sh_s[4][16];
    int tid = threadIdx.x;
    for (int i = tid; i < NBAS * HH; i += 256) rw1_s[i] = rw1[i];
    for (int i = tid; i < HH * 128; i += 256) ew_s[i] = edge_w[i];
    int w = tid >> 6, lane = tid & 63;
    int e = blockIdx.x * 4 + w;
    int src = ei[e], dst = ei[EE + e];
    float inv_r, u, pref, x, y, z;
    edge_geom(pos, src, dst, inv_r, u, pref, x, y, z);
    const float PI = 3.14159265358979f;
#pragma unroll
    for (int rep = 0; rep < 2; rep++) {
        int k = lane + rep * 64;
        rb_s[w][k] = pref * sinf(PI * (float)(k + 1) * u);
    }
    float shv[16];
    sph_all(x, y, z, shv);
    if (lane < 16) {
        float v = shv[0];
#pragma unroll
        for (int k = 1; k < 16; k++) v = (lane == k) ? shv[k] : v;
        sh_s[w][lane] = v;
    }
    if (lane < CC) g_s[w][lane] = f0[src * CC + lane] + f0[dst * CC + lane];
    __syncthreads();
    float acc = rb1[lane];
#pragma unroll 8
    for (int n = 0; n < NBAS; n++) acc += rb_s[w][n] * rw1_s[n * HH + lane];
    h_s[w][lane] = acc * sigmoidf_(acc);
    __syncthreads();
    size_t orow = ((size_t)NN + e) * 512;
#pragma unroll
    for (int rep = 0; rep < 2; rep++) {
        int o = lane + rep * 64;
        int l = o >> 5, c = o & 31;
        float a = edge_b[o];
#pragma unroll 8
        for (int j = 0; j < HH; j++) a += h_s[w][j] * ew_s[j * 128 + o];
        float base = a * g_s[w][c];
        int dl = 2 * l + 1, mo = l * l, co = 32 * l * l;
        for (int m = 0; m < dl; m++) out[orow + co + c * dl + m] = base * sh_s[w][mo + m];
    }
}

// ---------------------------------------------------------------------------
extern "C" void kernel_launch(void* const* d_in, const int* in_sizes, int n_in,
                              void* d_out, int out_size, void* d_ws, size_t ws_size,
                              hipStream_t stream) {
    const float* pos        = (const float*)d_in[0];
    const float* node_embed = (const float*)d_in[1];
    const float* rw1        = (const float*)d_in[2];
    const float* rb1        = (const float*)d_in[3];
    const float* rw2        = (const float*)d_in[4];
    const float* rb2        = (const float*)d_in[5];
    const float* self_w     = (const float*)d_in[6];
    const float* msg_w      = (const float*)d_in[7];
    const float* gate_w     = (const float*)d_in[8];
    const float* edge_w     = (const float*)d_in[9];
    const float* edge_b     = (const float*)d_in[10];
    const int* species      = (const int*)d_in[11];
    const int* ei           = (const int*)d_in[12];
    float* out = (float*)d_out;

    // --- workspace layout ---
    // base block: f0fin, f0ar, hbuf, shbuf, fA, agg, ints
    float* f0fin = (float*)d_ws;
    float* f0ar  = f0fin + (size_t)NN * CC;
    float* hbuf  = f0ar + (size_t)NN * CC;
    float* shbuf = hbuf + (size_t)EE * HH;
    float* fA    = shbuf + (size_t)EE * 16;
    float* agg   = fA + (size_t)NN * 512;
    int* deg     = (int*)(agg + (size_t)NN * 512);
    int* rowptr  = deg + NN;
    int* cursor  = rowptr + NN + 1;
    int* csr     = cursor + NN;
    size_t base_need = (size_t)((char*)(csr + EE) - (char*)d_ws);
    size_t extra_need = ((size_t)NN * 512 + (size_t)EE * 384) * 4;  // fB + aw(E,384)
    float* fB;
    float* aw;
    bool deep_fallback = false;
    if (ws_size >= base_need + extra_need) {
        fB = (float*)((char*)d_ws + base_need);
        aw = fB + (size_t)NN * 512;
    } else if (ws_size >= base_need) {
        // fB (20.5 MB) + aw384 (245.8 MB) fit in the 327.7 MB out edge region
        fB = out + (size_t)NN * 512;
        aw = fB + (size_t)NN * 512;
    } else {
        // deep fallback: everything in out edge region; aw only E*128 per layer
        deep_fallback = true;
        float* s = out + (size_t)NN * 512;
        hbuf = s; shbuf = hbuf + (size_t)EE * HH;
        fA = shbuf + (size_t)EE * 16;
        agg = fA + (size_t)NN * 512;
        fB = agg + (size_t)NN * 512;
        aw = fB + (size_t)NN * 512;                 // E*128
        deg = (int*)(aw + (size_t)EE * 128);
        rowptr = deg + NN; cursor = rowptr + NN + 1; csr = cursor + NN;
    }

    // CSR build
    hipMemsetAsync(deg, 0, (size_t)NN * 4, stream);
    hipMemsetAsync(cursor, 0, (size_t)NN * 4, stream);
    k_deg<<<(EE + 255) / 256, 256, 0, stream>>>(ei, deg);
    k_scan<<<1, 256, 0, stream>>>(deg, rowptr);
    k_scatter<<<(EE + 255) / 256, 256, 0, stream>>>(ei, rowptr, cursor, csr);

    k_init_f<<<(NN * CC * 16 + 255) / 256, 256, 0, stream>>>(node_embed, species, fA, f0ar);
    k_edge_pre<<<EE / 64, 256, 0, stream>>>(pos, rw1, rb1, ei, hbuf, shbuf);

    float* fc = fA;
    float* fn = fB;
    if (!deep_fallback) {
        // one fused GEMM for all three layer panels (unscaled, CSR order)
        k_gemm_all<<<EE / 64, 256, 0, stream>>>(hbuf, rw2, rb2, csr, aw, 0, 3, 384);
        for (int t = 0; t < LL; t++) {
            k_agg2<<<NN / 4, 256, 0, stream>>>(aw, shbuf, f0ar, ei, rowptr, csr, agg, t * 128, 384);
            float* f0o = (t == LL - 1) ? f0fin : f0ar;
            k_node<<<NN / 4, 256, 0, stream>>>(fc, agg, self_w, msg_w, gate_w, fn, f0o, t);
            float* tmp = fc; fc = fn; fn = tmp;
        }
        k_out_node<<<(NN * 512 + 255) / 256, 256, 0, stream>>>(fc, out);
        k_edge_out<<<EE / 64, 256, 0, stream>>>(hbuf, shbuf, edge_w, edge_b, f0fin, ei, out);
    } else {
        for (int t = 0; t < LL; t++) {
            k_gemm_all<<<EE / 64, 256, 0, stream>>>(hbuf, rw2, rb2, csr, aw, t, 1, 128);
            k_agg2<<<NN / 4, 256, 0, stream>>>(aw, shbuf, f0ar, ei, rowptr, csr, agg, 0, 128);
            float* f0o = (t == LL - 1) ? f0fin : f0ar;
            k_node<<<NN / 4, 256, 0, stream>>>(fc, agg, self_w, msg_w, gate_w, fn, f0o, t);
            float* tmp = fc; fc = fn; fn = tmp;
        }
        k_out_node<<<(NN * 512 + 255) / 256, 256, 0, stream>>>(fc, out);
        k_out_edge<<<EE / 4, 256, 0, stream>>>(pos, rw1, rb1, edge_w, edge_b, f0fin, ei, out);
    }
}

// Round 4
// 1132.523 us; speedup vs baseline: 1.1189x; 1.1189x over previous
//
#include <hip/hip_runtime.h>

#define NN 10000
#define EE 160000
#define CC 32
#define NBAS 128
#define HH 64
#define LL 3

__device__ __forceinline__ float sigmoidf_(float x) { return 1.0f / (1.0f + expf(-x)); }

// ---------------------------------------------------------------------------
__device__ __forceinline__ void edge_geom(const float* pos, int src, int dst,
                                          float& inv_r, float& u, float& pref,
                                          float& x, float& y, float& z) {
    float vx = pos[dst * 3 + 0] - pos[src * 3 + 0];
    float vy = pos[dst * 3 + 1] - pos[src * 3 + 1];
    float vz = pos[dst * 3 + 2] - pos[src * 3 + 2];
    float r2 = vx * vx + vy * vy + vz * vz + 1e-12f;
    float r = sqrtf(r2);
    inv_r = 1.0f / r;
    u = fminf(r * 0.2f, 1.0f);   // r/RC, RC=5
    const float PI = 3.14159265358979f;
    float env = 0.5f * (cosf(PI * u) + 1.0f);
    pref = env * 0.6324555320336759f * inv_r;  // sqrt(2/RC)
    x = vx * inv_r; y = vy * inv_r; z = vz * inv_r;
}

__device__ __forceinline__ void sph_all(float x, float y, float z, float* shv) {
    const float s3 = 1.7320508075688772f, s5 = 2.23606797749979f, s15 = 3.872983346207417f;
    const float c1 = 2.0916500663351885f;
    const float c2 = 10.246950765959598f;
    const float c3 = 1.6201851746019649f;
    const float c4 = 1.3228756555322954f;
    const float c5 = 5.123475382979799f;
    shv[0] = 1.0f;
    shv[1] = s3 * x; shv[2] = s3 * y; shv[3] = s3 * z;
    shv[4] = s15 * x * y;
    shv[5] = s15 * y * z;
    shv[6] = 0.5f * s5 * (3.0f * z * z - 1.0f);
    shv[7] = s15 * x * z;
    shv[8] = 0.5f * s15 * (x * x - y * y);
    shv[9]  = c1 * y * (3.0f * x * x - y * y);
    shv[10] = c2 * x * y * z;
    shv[11] = c3 * y * (5.0f * z * z - 1.0f);
    shv[12] = c4 * (5.0f * z * z * z - 3.0f * z);
    shv[13] = c3 * x * (5.0f * z * z - 1.0f);
    shv[14] = c5 * z * (x * x - y * y);
    shv[15] = c1 * x * (x * x - 3.0f * y * y);
}

// ---------------------------------------------------------------------------
// CSR build
__global__ void k_deg(const int* __restrict__ ei, int* __restrict__ deg) {
    int e = blockIdx.x * blockDim.x + threadIdx.x;
    if (e < EE) atomicAdd(&deg[ei[EE + e]], 1);
}

__global__ __launch_bounds__(256) void k_scan(const int* __restrict__ deg, int* __restrict__ rowptr) {
    __shared__ int part[256];
    const int CHUNK = 40;  // 256*40 = 10240 >= NN
    int tid = threadIdx.x;
    int s = 0;
#pragma unroll
    for (int k = 0; k < CHUNK; k++) {
        int idx = tid * CHUNK + k;
        if (idx < NN) s += deg[idx];
    }
    part[tid] = s;
    __syncthreads();
    for (int off = 1; off < 256; off <<= 1) {
        int v = (tid >= off) ? part[tid - off] : 0;
        __syncthreads();
        part[tid] += v;
        __syncthreads();
    }
    int run = (tid > 0) ? part[tid - 1] : 0;
#pragma unroll
    for (int k = 0; k < CHUNK; k++) {
        int idx = tid * CHUNK + k;
        if (idx < NN) { rowptr[idx] = run; run += deg[idx]; }
    }
    if (tid == 255) rowptr[NN] = run;  // == EE
}

__global__ void k_scatter(const int* __restrict__ ei, const int* __restrict__ rowptr,
                          int* __restrict__ cursor, int* __restrict__ csr) {
    int e = blockIdx.x * blockDim.x + threadIdx.x;
    if (e >= EE) return;
    int d = ei[EE + e];
    int slot = atomicAdd(&cursor[d], 1);
    csr[rowptr[d] + slot] = e;
}

// ---------------------------------------------------------------------------
// compact f0 init only (the full f array for t=0 is implicit: m==0 -> f0, else 0)
__global__ void k_init_f0(const float* __restrict__ ne, const int* __restrict__ species,
                          float* __restrict__ f0) {
    int idx = blockIdx.x * blockDim.x + threadIdx.x;
    if (idx >= NN * CC) return;
    int c = idx & 31;
    int n = idx >> 5;
    f0[idx] = ne[species[n] * CC + c];
}

// ---------------------------------------------------------------------------
// K1: 64-edge tile. Phase A: geometry + sh + radial basis via Chebyshev
// recurrence re-anchored every 16 bases (4 sinf per thread).
// Phase B: register-tile GEMM rb(64x128) @ rw1(128x64) -> silu -> hbuf.
__global__ __launch_bounds__(256) void k_edge_pre(
    const float* __restrict__ pos, const float* __restrict__ rw1, const float* __restrict__ rb1,
    const int* __restrict__ ei, float* __restrict__ hbuf, float* __restrict__ shbuf) {
    __shared__ float rw1_s[NBAS * HH];     // 32 KB  [k][h]
    __shared__ float rb_s[64 * 132];       // 33 KB  [edge][k], pad->132
    int tid = threadIdx.x;
    int ebase = blockIdx.x * 64;
    for (int i = tid; i < NBAS * HH / 4; i += 256)
        *(float4*)&rw1_s[i * 4] = *(const float4*)&rw1[i * 4];
    // Phase A: 4 threads per edge, each covers 32 contiguous bases
    {
        int r = tid >> 2, q = tid & 3;
        int e = ebase + r;
        int src = ei[e], dst = ei[EE + e];
        float inv_r, u, pref, x, y, z;
        edge_geom(pos, src, dst, inv_r, u, pref, x, y, z);
        float shv[16];
        sph_all(x, y, z, shv);
        float4 sv;
        sv.x = shv[q * 4 + 0]; sv.y = shv[q * 4 + 1];
        sv.z = shv[q * 4 + 2]; sv.w = shv[q * 4 + 3];
        *(float4*)&shbuf[(size_t)e * 16 + q * 4] = sv;
        const float PI = 3.14159265358979f;
        float th = PI * u;
        float tc = 2.0f * cosf(th);
        float* rp = &rb_s[r * 132 + 32 * q];
        int n0 = 32 * q + 1;
#pragma unroll
        for (int g = 0; g < 2; g++) {
            int nb = n0 + 16 * g;
            float sm1 = sinf(th * (float)nb);
            float s0 = sinf(th * (float)(nb + 1));
            rp[16 * g + 0] = pref * sm1;
            rp[16 * g + 1] = pref * s0;
#pragma unroll
            for (int j = 2; j < 16; j++) {
                float s = tc * s0 - sm1;
                sm1 = s0; s0 = s;
                rp[16 * g + j] = pref * s;
            }
        }
    }
    __syncthreads();
    // Phase B: 64x64 tile GEMM, K=128; 4 rows x 4 cols per thread
    int col0 = (tid & 15) * 4;
    int r0 = (tid >> 4) * 4;
    float acc[4][4];
#pragma unroll
    for (int i = 0; i < 4; i++) { acc[i][0] = 0.f; acc[i][1] = 0.f; acc[i][2] = 0.f; acc[i][3] = 0.f; }
#pragma unroll 2
    for (int k0 = 0; k0 < NBAS; k0 += 4) {
        float4 w0 = *(float4*)&rw1_s[(k0 + 0) * HH + col0];
        float4 w1 = *(float4*)&rw1_s[(k0 + 1) * HH + col0];
        float4 w2 = *(float4*)&rw1_s[(k0 + 2) * HH + col0];
        float4 w3 = *(float4*)&rw1_s[(k0 + 3) * HH + col0];
#pragma unroll
        for (int i = 0; i < 4; i++) {
            float4 rv = *(float4*)&rb_s[(r0 + i) * 132 + k0];
            acc[i][0] += rv.x * w0.x; acc[i][1] += rv.x * w0.y; acc[i][2] += rv.x * w0.z; acc[i][3] += rv.x * w0.w;
            acc[i][0] += rv.y * w1.x; acc[i][1] += rv.y * w1.y; acc[i][2] += rv.y * w1.z; acc[i][3] += rv.y * w1.w;
            acc[i][0] += rv.z * w2.x; acc[i][1] += rv.z * w2.y; acc[i][2] += rv.z * w2.z; acc[i][3] += rv.z * w2.w;
            acc[i][0] += rv.w * w3.x; acc[i][1] += rv.w * w3.y; acc[i][2] += rv.w * w3.z; acc[i][3] += rv.w * w3.w;
        }
    }
    float4 bv = *(const float4*)&rb1[col0];
#pragma unroll
    for (int i = 0; i < 4; i++) {
        float a0 = acc[i][0] + bv.x, a1 = acc[i][1] + bv.y;
        float a2 = acc[i][2] + bv.z, a3 = acc[i][3] + bv.w;
        float4 hres;
        hres.x = a0 * sigmoidf_(a0); hres.y = a1 * sigmoidf_(a1);
        hres.z = a2 * sigmoidf_(a2); hres.w = a3 * sigmoidf_(a3);
        *(float4*)&hbuf[(size_t)(ebase + r0 + i) * HH + col0] = hres;
    }
}

// ---------------------------------------------------------------------------
// K2a: one h-staging serves npanel panels; each panel written to its OWN
// contiguous [E][128] buffer (de-interleaved -> k_aggnode reads sequential).
__global__ __launch_bounds__(256) void k_gemm_all(
    const float* __restrict__ hbuf, const float* __restrict__ rw2,
    const float* __restrict__ rb2, const int* __restrict__ csr,
    float* __restrict__ aw, int panel0, int npanel) {
    __shared__ float w_s[HH * 128];      // 32 KB [k][o]
    __shared__ float h_s[64][68];        // 17 KB
    int tid = threadIdx.x;
    int pbase = blockIdx.x * 64;
    {
        int r = tid >> 2, q = tid & 3;
        int e = csr[pbase + r];
        const float4* hp = (const float4*)(hbuf + (size_t)e * HH + q * 16);
        float4 v0 = hp[0], v1 = hp[1], v2 = hp[2], v3 = hp[3];
        float4* dp = (float4*)&h_s[r][q * 16];
        dp[0] = v0; dp[1] = v1; dp[2] = v2; dp[3] = v3;
    }
    int ob = (tid & 31) << 2;
    int r0 = (tid >> 5) << 3;
    for (int p = 0; p < npanel; p++) {
        int wcol = (panel0 + p) * 128;
        __syncthreads();   // h_s ready (p=0) / previous compute finished
        for (int i = tid; i < HH * 32; i += 256) {
            int j = i >> 5, o4 = (i & 31) << 2;
            *(float4*)&w_s[j * 128 + o4] = *(const float4*)&rw2[(size_t)j * 384 + wcol + o4];
        }
        __syncthreads();
        float acc[8][4];
#pragma unroll
        for (int i = 0; i < 8; i++) { acc[i][0] = 0.f; acc[i][1] = 0.f; acc[i][2] = 0.f; acc[i][3] = 0.f; }
#pragma unroll 2
        for (int k0 = 0; k0 < HH; k0 += 4) {
            float4 w0 = *(float4*)&w_s[(k0 + 0) * 128 + ob];
            float4 w1 = *(float4*)&w_s[(k0 + 1) * 128 + ob];
            float4 w2 = *(float4*)&w_s[(k0 + 2) * 128 + ob];
            float4 w3 = *(float4*)&w_s[(k0 + 3) * 128 + ob];
#pragma unroll
            for (int i = 0; i < 8; i++) {
                float4 hv = *(float4*)&h_s[r0 + i][k0];
                acc[i][0] += hv.x * w0.x; acc[i][1] += hv.x * w0.y; acc[i][2] += hv.x * w0.z; acc[i][3] += hv.x * w0.w;
                acc[i][0] += hv.y * w1.x; acc[i][1] += hv.y * w1.y; acc[i][2] += hv.y * w1.z; acc[i][3] += hv.y * w1.w;
                acc[i][0] += hv.z * w2.x; acc[i][1] += hv.z * w2.y; acc[i][2] += hv.z * w2.z; acc[i][3] += hv.z * w2.w;
                acc[i][0] += hv.w * w3.x; acc[i][1] += hv.w * w3.y; acc[i][2] += hv.w * w3.z; acc[i][3] += hv.w * w3.w;
            }
        }
        float4 bv = *(const float4*)&rb2[wcol + ob];
        float* awp = aw + (size_t)p * EE * 128;
#pragma unroll
        for (int i = 0; i < 8; i++) {
            float4 res;
            res.x = acc[i][0] + bv.x; res.y = acc[i][1] + bv.y;
            res.z = acc[i][2] + bv.z; res.w = acc[i][3] + bv.w;
            *(float4*)&awp[(size_t)(pbase + r0 + i) * 128 + ob] = res;
        }
    }
}

// ---------------------------------------------------------------------------
// K2b+K3 fused: per-node CSR gather aggregation (sequential aw stream) +
// node update in the same wave. agg never touches HBM.
// INIT: layer-0 input f is implicit (m==0 -> f0prev, else 0); f_cur unused.
// FINAL: writes node output directly in final layout + f0fin.
// f0 ping-pong (f0prev read-only, f0_out separate) avoids the fused race.
template<int INIT, int FINAL>
__global__ __launch_bounds__(256) void k_aggnode(
    const float* __restrict__ aw, const float* __restrict__ shbuf,
    const float* __restrict__ f0prev, const float* __restrict__ f_cur,
    const int* __restrict__ ei, const int* __restrict__ rowptr,
    const int* __restrict__ csr,
    const float* __restrict__ self_w, const float* __restrict__ msg_w,
    const float* __restrict__ gate_w,
    float* __restrict__ f_next, float* __restrict__ f0_out, int t) {
    __shared__ float agg_s[4][CC * 17];   // pad 17: stride-16 writes were 16-way conflicts
    __shared__ float new_s[4][CC * 17];
    __shared__ float gate_s[4][CC];
    int w = threadIdx.x >> 6, lane = threadIdx.x & 63;
    int n = blockIdx.x * 4 + w;
    int c = lane & 31;
    int half = lane >> 5;
    float acc0[3] = {0.f, 0.f, 0.f};
    float acc1[7] = {0.f, 0.f, 0.f, 0.f, 0.f, 0.f, 0.f};
    int beg = rowptr[n], end = rowptr[n + 1];
    for (int k = beg; k < end; k++) {
        int e = csr[k];
        int src = ei[e];
        float fs = f0prev[src * CC + c];
        float a0 = aw[(size_t)k * 128 + lane] * fs;        // sequential 512 B/edge
        float a1 = aw[(size_t)k * 128 + 64 + lane] * fs;
        const float4* shp = (const float4*)(shbuf + (size_t)e * 16);
        float4 s0 = shp[0], s1 = shp[1], s2 = shp[2], s3 = shp[3];
        if (half == 0) {
            acc0[0] += a0 * s0.x;                                          // l=0
            acc1[0] += a1 * s1.x; acc1[1] += a1 * s1.y;                    // l=2
            acc1[2] += a1 * s1.z; acc1[3] += a1 * s1.w; acc1[4] += a1 * s2.x;
        } else {
            acc0[0] += a0 * s0.y; acc0[1] += a0 * s0.z; acc0[2] += a0 * s0.w;   // l=1
            acc1[0] += a1 * s2.y; acc1[1] += a1 * s2.z; acc1[2] += a1 * s2.w;   // l=3
            acc1[3] += a1 * s3.x; acc1[4] += a1 * s3.y; acc1[5] += a1 * s3.z; acc1[6] += a1 * s3.w;
        }
    }
    // stage aggregate to LDS (wave-local; same-wave ordering via lgkmcnt)
    {
        int l0 = half, dl0 = 2 * l0 + 1, mo0 = l0 * l0;
        int l1 = 2 + half, dl1 = 2 * l1 + 1, mo1 = l1 * l1;
        float* ap = &agg_s[w][c * 17];
#pragma unroll
        for (int m = 0; m < 3; m++)
            if (m < dl0) ap[mo0 + m] = acc0[m];
#pragma unroll
        for (int m = 0; m < 7; m++)
            if (m < dl1) ap[mo1 + m] = acc1[m];
    }
    // node update: d = c, m-group = half (same mapping as old k_node)
    int d = c, mg = half;
#pragma unroll
    for (int k = 0; k < 8; k++) {
        int m = mg + 2 * k;
        int l = (m == 0) ? 0 : (m < 4) ? 1 : (m < 9) ? 2 : 3;
        const float* sw = self_w + (size_t)((t * 4 + l) * CC) * CC + d;
        const float* mw = msg_w + (size_t)((t * 4 + l) * CC) * CC + d;
        float acc = 0.0f;
#pragma unroll 8
        for (int c2 = 0; c2 < CC; c2++) {
            float fv;
            if (INIT) fv = (m == 0) ? f0prev[n * CC + c2] : 0.0f;
            else fv = f_cur[((size_t)n * CC + c2) * 16 + m];
            acc += fv * sw[c2 * CC] + agg_s[w][c2 * 17 + m] * mw[c2 * CC];
        }
        new_s[w][d * 17 + m] = acc;
    }
    if (mg == 0) {
        float g = 0.0f;
#pragma unroll 8
        for (int c2 = 0; c2 < CC; c2++)
            g += new_s[w][c2 * 17 + 0] * gate_w[((size_t)t * CC + c2) * CC + d];
        gate_s[w][d] = sigmoidf_(g);
    }
#pragma unroll
    for (int k = 0; k < 8; k++) {
        int m = mg + 2 * k;
        float v = new_s[w][d * 17 + m];
        if (m == 0) v = v * sigmoidf_(v);
        else v *= gate_s[w][d];
        if (FINAL) {
            int l = (m == 0) ? 0 : (m < 4) ? 1 : (m < 9) ? 2 : 3;
            f_next[(size_t)n * 512 + 32 * l * l + d * (2 * l + 1) + (m - l * l)] = v;
        } else {
            f_next[((size_t)n * CC + d) * 16 + m] = v;
        }
        if (m == 0) f0_out[n * CC + d] = v;
    }
}

// ---------------------------------------------------------------------------
// helper: emit one row-segment of edge output
template<int DL>
__device__ __forceinline__ void emit_edge(float* outp, const float* shp,
                                          float e0, float e1, float e2, float e3) {
    float ew[4] = {e0, e1, e2, e3};
    float buf[4 * DL];
#pragma unroll
    for (int cc = 0; cc < 4; cc++)
#pragma unroll
        for (int m = 0; m < DL; m++) buf[cc * DL + m] = ew[cc] * shp[m];
#pragma unroll
    for (int t = 0; t < DL; t++) *(float4*)&outp[t * 4] = *(float4*)&buf[t * 4];
}

// ---------------------------------------------------------------------------
// K4b (fused): edge-output GEMM + sh expansion
__global__ __launch_bounds__(256) void k_edge_out(
    const float* __restrict__ hbuf, const float* __restrict__ shbuf,
    const float* __restrict__ edge_w, const float* __restrict__ edge_b,
    const float* __restrict__ f0, const int* __restrict__ ei,
    float* __restrict__ out) {
    __shared__ float w_s[HH * 128];      // 32 KB
    __shared__ float h_s[64][68];        // 17 KB
    __shared__ float sh_s[64][16];       // 4 KB
    int tid = threadIdx.x;
    int ebase = blockIdx.x * 64;
    for (int i = tid; i < HH * 32; i += 256) {
        int j = i >> 5, o4 = (i & 31) << 2;
        *(float4*)&w_s[j * 128 + o4] = *(const float4*)&edge_w[(size_t)j * 128 + o4];
    }
    {
        int r = tid >> 2, q = tid & 3;
        int e = ebase + r;
        const float4* hp = (const float4*)(hbuf + (size_t)e * HH + q * 16);
        float4 v0 = hp[0], v1 = hp[1], v2 = hp[2], v3 = hp[3];
        float4* dp = (float4*)&h_s[r][q * 16];
        dp[0] = v0; dp[1] = v1; dp[2] = v2; dp[3] = v3;
        *(float4*)&sh_s[r][q * 4] = *(const float4*)&shbuf[(size_t)e * 16 + q * 4];
    }
    __syncthreads();
    int ob = (tid & 31) << 2;
    int r0 = (tid >> 5) << 3;
    float acc[8][4];
#pragma unroll
    for (int i = 0; i < 8; i++) { acc[i][0] = 0.f; acc[i][1] = 0.f; acc[i][2] = 0.f; acc[i][3] = 0.f; }
#pragma unroll 2
    for (int k0 = 0; k0 < HH; k0 += 4) {
        float4 w0 = *(float4*)&w_s[(k0 + 0) * 128 + ob];
        float4 w1 = *(float4*)&w_s[(k0 + 1) * 128 + ob];
        float4 w2 = *(float4*)&w_s[(k0 + 2) * 128 + ob];
        float4 w3 = *(float4*)&w_s[(k0 + 3) * 128 + ob];
#pragma unroll
        for (int i = 0; i < 8; i++) {
            float4 hv = *(float4*)&h_s[r0 + i][k0];
            acc[i][0] += hv.x * w0.x; acc[i][1] += hv.x * w0.y; acc[i][2] += hv.x * w0.z; acc[i][3] += hv.x * w0.w;
            acc[i][0] += hv.y * w1.x; acc[i][1] += hv.y * w1.y; acc[i][2] += hv.y * w1.z; acc[i][3] += hv.y * w1.w;
            acc[i][0] += hv.z * w2.x; acc[i][1] += hv.z * w2.y; acc[i][2] += hv.z * w2.z; acc[i][3] += hv.z * w2.w;
            acc[i][0] += hv.w * w3.x; acc[i][1] += hv.w * w3.y; acc[i][2] += hv.w * w3.z; acc[i][3] += hv.w * w3.w;
        }
    }
    float4 bv = *(const float4*)&edge_b[ob];
    int l = ob >> 5;
    int cbase = ob & 31;
    int dl = 2 * l + 1, mo = l * l, co = 32 * l * l;
#pragma unroll
    for (int i = 0; i < 8; i++) {
        int rr = r0 + i;
        int e = ebase + rr;
        int src = ei[e], dst = ei[EE + e];
        float4 g1 = *(const float4*)&f0[src * CC + cbase];
        float4 g2 = *(const float4*)&f0[dst * CC + cbase];
        float e0 = (acc[i][0] + bv.x) * (g1.x + g2.x);
        float e1 = (acc[i][1] + bv.y) * (g1.y + g2.y);
        float e2 = (acc[i][2] + bv.z) * (g1.z + g2.z);
        float e3 = (acc[i][3] + bv.w) * (g1.w + g2.w);
        float* outp = out + ((size_t)NN + e) * 512 + co + (size_t)cbase * dl;
        const float* shp = &sh_s[rr][mo];
        if (l == 0)      emit_edge<1>(outp, shp, e0, e1, e2, e3);
        else if (l == 1) emit_edge<3>(outp, shp, e0, e1, e2, e3);
        else if (l == 2) emit_edge<5>(outp, shp, e0, e1, e2, e3);
        else             emit_edge<7>(outp, shp, e0, e1, e2, e3);
    }
}

// ---------------------------------------------------------------------------
// K4b deep-fallback: recomputes h and sh from pos
__global__ __launch_bounds__(256) void k_out_edge(
    const float* __restrict__ pos, const float* __restrict__ rw1, const float* __restrict__ rb1,
    const float* __restrict__ edge_w, const float* __restrict__ edge_b,
    const float* __restrict__ f0, const int* __restrict__ ei, float* __restrict__ out) {
    __shared__ float rw1_s[NBAS * HH];
    __shared__ float ew_s[HH * 128];
    __shared__ float rb_s[4][NBAS];
    __shared__ float h_s[4][HH];
    __shared__ float g_s[4][CC];
    __shared__ float sh_s[4][16];
    int tid = threadIdx.x;
    for (int i = tid; i < NBAS * HH; i += 256) rw1_s[i] = rw1[i];
    for (int i = tid; i < HH * 128; i += 256) ew_s[i] = edge_w[i];
    int w = tid >> 6, lane = tid & 63;
    int e = blockIdx.x * 4 + w;
    int src = ei[e], dst = ei[EE + e];
    float inv_r, u, pref, x, y, z;
    edge_geom(pos, src, dst, inv_r, u, pref, x, y, z);
    const float PI = 3.14159265358979f;
#pragma unroll
    for (int rep = 0; rep < 2; rep++) {
        int k = lane + rep * 64;
        rb_s[w][k] = pref * sinf(PI * (float)(k + 1) * u);
    }
    float shv[16];
    sph_all(x, y, z, shv);
    if (lane < 16) {
        float v = shv[0];
#pragma unroll
        for (int k = 1; k < 16; k++) v = (lane == k) ? shv[k] : v;
        sh_s[w][lane] = v;
    }
    if (lane < CC) g_s[w][lane] = f0[src * CC + lane] + f0[dst * CC + lane];
    __syncthreads();
    float acc = rb1[lane];
#pragma unroll 8
    for (int n = 0; n < NBAS; n++) acc += rb_s[w][n] * rw1_s[n * HH + lane];
    h_s[w][lane] = acc * sigmoidf_(acc);
    __syncthreads();
    size_t orow = ((size_t)NN + e) * 512;
#pragma unroll
    for (int rep = 0; rep < 2; rep++) {
        int o = lane + rep * 64;
        int l = o >> 5, c = o & 31;
        float a = edge_b[o];
#pragma unroll 8
        for (int j = 0; j < HH; j++) a += h_s[w][j] * ew_s[j * 128 + o];
        float base = a * g_s[w][c];
        int dl = 2 * l + 1, mo = l * l, co = 32 * l * l;
        for (int m = 0; m < dl; m++) out[orow + co + c * dl + m] = base * sh_s[w][mo + m];
    }
}

// ---------------------------------------------------------------------------
extern "C" void kernel_launch(void* const* d_in, const int* in_sizes, int n_in,
                              void* d_out, int out_size, void* d_ws, size_t ws_size,
                              hipStream_t stream) {
    const float* pos        = (const float*)d_in[0];
    const float* node_embed = (const float*)d_in[1];
    const float* rw1        = (const float*)d_in[2];
    const float* rb1        = (const float*)d_in[3];
    const float* rw2        = (const float*)d_in[4];
    const float* rb2        = (const float*)d_in[5];
    const float* self_w     = (const float*)d_in[6];
    const float* msg_w      = (const float*)d_in[7];
    const float* gate_w     = (const float*)d_in[8];
    const float* edge_w     = (const float*)d_in[9];
    const float* edge_b     = (const float*)d_in[10];
    const int* species      = (const int*)d_in[11];
    const int* ei           = (const int*)d_in[12];
    float* out = (float*)d_out;

    // --- workspace layout ---
    float* f0fin = (float*)d_ws;
    float* f0A   = f0fin + (size_t)NN * CC;
    float* f0B   = f0A + (size_t)NN * CC;
    float* hbuf  = f0B + (size_t)NN * CC;
    float* shbuf = hbuf + (size_t)EE * HH;
    float* fA    = shbuf + (size_t)EE * 16;
    int* deg     = (int*)(fA + (size_t)NN * 512);
    int* rowptr  = deg + NN;
    int* cursor  = rowptr + NN + 1;
    int* csr     = cursor + NN;
    size_t base_need = (size_t)((char*)(csr + EE) - (char*)d_ws);
    size_t extra_need = ((size_t)NN * 512 + (size_t)EE * 384) * 4;  // fB + aw(3 x E x 128)
    float* fB;
    float* aw;
    bool deep_fallback = false;
    if (ws_size >= base_need + extra_need) {
        fB = (float*)((char*)d_ws + base_need);
        aw = fB + (size_t)NN * 512;
    } else if (ws_size >= base_need) {
        // fB (20.5 MB) + aw (245.8 MB) in the 327.7 MB out edge region
        fB = out + (size_t)NN * 512;
        aw = fB + (size_t)NN * 512;
    } else {
        // deep fallback: scratch in out edge region; aw only E*128 per layer
        deep_fallback = true;
        float* s = out + (size_t)NN * 512;
        hbuf = s; shbuf = hbuf + (size_t)EE * HH;
        fA = shbuf + (size_t)EE * 16;
        fB = fA + (size_t)NN * 512;
        aw = fB + (size_t)NN * 512;                 // E*128
        deg = (int*)(aw + (size_t)EE * 128);
        rowptr = deg + NN; cursor = rowptr + NN + 1; csr = cursor + NN;
    }

    // CSR build
    hipMemsetAsync(deg, 0, (size_t)NN * 4, stream);
    hipMemsetAsync(cursor, 0, (size_t)NN * 4, stream);
    k_deg<<<(EE + 255) / 256, 256, 0, stream>>>(ei, deg);
    k_scan<<<1, 256, 0, stream>>>(deg, rowptr);
    k_scatter<<<(EE + 255) / 256, 256, 0, stream>>>(ei, rowptr, cursor, csr);

    k_init_f0<<<(NN * CC + 255) / 256, 256, 0, stream>>>(node_embed, species, f0A);
    k_edge_pre<<<EE / 64, 256, 0, stream>>>(pos, rw1, rb1, ei, hbuf, shbuf);

    if (!deep_fallback) {
        k_gemm_all<<<EE / 64, 256, 0, stream>>>(hbuf, rw2, rb2, csr, aw, 0, 3);
        k_aggnode<1, 0><<<NN / 4, 256, 0, stream>>>(aw, shbuf, f0A, nullptr,
            ei, rowptr, csr, self_w, msg_w, gate_w, fA, f0B, 0);
        k_aggnode<0, 0><<<NN / 4, 256, 0, stream>>>(aw + (size_t)EE * 128, shbuf, f0B, fA,
            ei, rowptr, csr, self_w, msg_w, gate_w, fB, f0A, 1);
        k_aggnode<0, 1><<<NN / 4, 256, 0, stream>>>(aw + (size_t)2 * EE * 128, shbuf, f0A, fB,
            ei, rowptr, csr, self_w, msg_w, gate_w, out, f0fin, 2);
        k_edge_out<<<EE / 64, 256, 0, stream>>>(hbuf, shbuf, edge_w, edge_b, f0fin, ei, out);
    } else {
        // per-layer GEMM into single-panel aw
        k_gemm_all<<<EE / 64, 256, 0, stream>>>(hbuf, rw2, rb2, csr, aw, 0, 1);
        k_aggnode<1, 0><<<NN / 4, 256, 0, stream>>>(aw, shbuf, f0A, nullptr,
            ei, rowptr, csr, self_w, msg_w, gate_w, fA, f0B, 0);
        k_gemm_all<<<EE / 64, 256, 0, stream>>>(hbuf, rw2, rb2, csr, aw, 1, 1);
        k_aggnode<0, 0><<<NN / 4, 256, 0, stream>>>(aw, shbuf, f0B, fA,
            ei, rowptr, csr, self_w, msg_w, gate_w, fB, f0A, 1);
        k_gemm_all<<<EE / 64, 256, 0, stream>>>(hbuf, rw2, rb2, csr, aw, 2, 1);
        k_aggnode<0, 1><<<NN / 4, 256, 0, stream>>>(aw, shbuf, f0A, fB,
            ei, rowptr, csr, self_w, msg_w, gate_w, out, f0fin, 2);
        k_out_edge<<<EE / 4, 256, 0, stream>>>(pos, rw1, rb1, edge_w, edge_b, f0fin, ei, out);
    }
}

// Round 6
// 1016.714 us; speedup vs baseline: 1.2464x; 1.1139x over previous
//
#include <hip/hip_runtime.h>

#define NN 10000
#define EE 160000
#define CC 32
#define NBAS 128
#define HH 64
#define LL 3

__device__ __forceinline__ float sigmoidf_(float x) { return 1.0f / (1.0f + expf(-x)); }

// bf16 helpers (round-to-nearest-even)
__device__ __forceinline__ unsigned short f2bf(float f) {
    unsigned int u = __float_as_uint(f);
    unsigned int r = u + 0x7FFFu + ((u >> 16) & 1u);
    return (unsigned short)(r >> 16);
}
__device__ __forceinline__ float bf2f(unsigned short h) {
    return __uint_as_float(((unsigned int)h) << 16);
}

// ---------------------------------------------------------------------------
__device__ __forceinline__ void edge_geom(const float* pos, int src, int dst,
                                          float& inv_r, float& u, float& pref,
                                          float& x, float& y, float& z) {
    float vx = pos[dst * 3 + 0] - pos[src * 3 + 0];
    float vy = pos[dst * 3 + 1] - pos[src * 3 + 1];
    float vz = pos[dst * 3 + 2] - pos[src * 3 + 2];
    float r2 = vx * vx + vy * vy + vz * vz + 1e-12f;
    float r = sqrtf(r2);
    inv_r = 1.0f / r;
    u = fminf(r * 0.2f, 1.0f);   // r/RC, RC=5
    const float PI = 3.14159265358979f;
    float env = 0.5f * (cosf(PI * u) + 1.0f);
    pref = env * 0.6324555320336759f * inv_r;  // sqrt(2/RC)
    x = vx * inv_r; y = vy * inv_r; z = vz * inv_r;
}

__device__ __forceinline__ void sph_all(float x, float y, float z, float* shv) {
    const float s3 = 1.7320508075688772f, s5 = 2.23606797749979f, s15 = 3.872983346207417f;
    const float c1 = 2.0916500663351885f;
    const float c2 = 10.246950765959598f;
    const float c3 = 1.6201851746019649f;
    const float c4 = 1.3228756555322954f;
    const float c5 = 5.123475382979799f;
    shv[0] = 1.0f;
    shv[1] = s3 * x; shv[2] = s3 * y; shv[3] = s3 * z;
    shv[4] = s15 * x * y;
    shv[5] = s15 * y * z;
    shv[6] = 0.5f * s5 * (3.0f * z * z - 1.0f);
    shv[7] = s15 * x * z;
    shv[8] = 0.5f * s15 * (x * x - y * y);
    shv[9]  = c1 * y * (3.0f * x * x - y * y);
    shv[10] = c2 * x * y * z;
    shv[11] = c3 * y * (5.0f * z * z - 1.0f);
    shv[12] = c4 * (5.0f * z * z * z - 3.0f * z);
    shv[13] = c3 * x * (5.0f * z * z - 1.0f);
    shv[14] = c5 * z * (x * x - y * y);
    shv[15] = c1 * x * (x * x - 3.0f * y * y);
}

// ---------------------------------------------------------------------------
// CSR build
__global__ void k_deg(const int* __restrict__ ei, int* __restrict__ deg) {
    int e = blockIdx.x * blockDim.x + threadIdx.x;
    if (e < EE) atomicAdd(&deg[ei[EE + e]], 1);
}

__global__ __launch_bounds__(256) void k_scan(const int* __restrict__ deg, int* __restrict__ rowptr) {
    __shared__ int part[256];
    const int CHUNK = 40;  // 256*40 = 10240 >= NN
    int tid = threadIdx.x;
    int s = 0;
#pragma unroll
    for (int k = 0; k < CHUNK; k++) {
        int idx = tid * CHUNK + k;
        if (idx < NN) s += deg[idx];
    }
    part[tid] = s;
    __syncthreads();
    for (int off = 1; off < 256; off <<= 1) {
        int v = (tid >= off) ? part[tid - off] : 0;
        __syncthreads();
        part[tid] += v;
        __syncthreads();
    }
    int run = (tid > 0) ? part[tid - 1] : 0;
#pragma unroll
    for (int k = 0; k < CHUNK; k++) {
        int idx = tid * CHUNK + k;
        if (idx < NN) { rowptr[idx] = run; run += deg[idx]; }
    }
    if (tid == 255) rowptr[NN] = run;  // == EE
}

// scatter: writes inverse permutation ipos[e] (edge -> CSR position) and
// srcc[p] = src node of the edge at CSR position p (makes k_aggnode streaming)
__global__ void k_scatter(const int* __restrict__ ei, const int* __restrict__ rowptr,
                          int* __restrict__ cursor, int* __restrict__ ipos,
                          int* __restrict__ srcc) {
    int e = blockIdx.x * blockDim.x + threadIdx.x;
    if (e >= EE) return;
    int d = ei[EE + e];
    int s = ei[e];
    int slot = atomicAdd(&cursor[d], 1);
    int p = rowptr[d] + slot;
    ipos[e] = p;
    srcc[p] = s;
}

// ---------------------------------------------------------------------------
// compact f0 init (full f at t=0 is implicit: m==0 -> f0, else 0)
__global__ void k_init_f0(const float* __restrict__ ne, const int* __restrict__ species,
                          float* __restrict__ f0) {
    int idx = blockIdx.x * blockDim.x + threadIdx.x;
    if (idx >= NN * CC) return;
    int c = idx & 31;
    int n = idx >> 5;
    f0[idx] = ne[species[n] * CC + c];
}

// ---------------------------------------------------------------------------
// K1 (fused): per 64-edge tile:
//   Phase A: geometry + sh (-> shbuf edge-order, shc CSR-order) + radial basis
//            (Chebyshev, re-anchored every 16 bases)
//   Phase B: h = silu(rb(64x128) @ rw1(128x64) + rb1) -> hbuf + LDS
//   Phase C: 3 panels of aw[p][csr_pos] = bf16(h @ rw2_panel + rb2), scattered
//            to CSR positions via ipos (so k_aggnode reads sequentially).
// LDS: w_s 32 KB (rw1, then rw2 panels) + rb_s 33 KB (then h_s overlay) -> 2 blk/CU
__global__ __launch_bounds__(256) void k_edge_pre(
    const float* __restrict__ pos, const float* __restrict__ rw1, const float* __restrict__ rb1,
    const float* __restrict__ rw2, const float* __restrict__ rb2,
    const int* __restrict__ ei, const int* __restrict__ ipos,
    float* __restrict__ hbuf, float* __restrict__ shbuf, float* __restrict__ shc,
    unsigned short* __restrict__ awh) {
    __shared__ float w_s[NBAS * HH];       // 32 KB: rw1 [k][h], later rw2 panel [j][o]
    __shared__ float rb_s[64 * 132];       // 33 KB: [edge][k] pad->132; later h_s[64][68]
    __shared__ int ip_s[64];
    float* h_s = rb_s;                     // overlay after phase B
    int tid = threadIdx.x;
    int ebase = blockIdx.x * 64;
    // stage rw1 (row-major [k][h])
    for (int i = tid; i < NBAS * HH / 4; i += 256)
        *(float4*)&w_s[i * 4] = *(const float4*)&rw1[i * 4];
    // ---- Phase A: 4 threads per edge, each covers 32 contiguous bases
    {
        int r = tid >> 2, q = tid & 3;
        int e = ebase + r;
        int ip = ipos[e];
        if (q == 0) ip_s[r] = ip;
        int src = ei[e], dst = ei[EE + e];
        float inv_r, u, pref, x, y, z;
        edge_geom(pos, src, dst, inv_r, u, pref, x, y, z);
        float shv[16];
        sph_all(x, y, z, shv);
        float4 sv;
        sv.x = shv[q * 4 + 0]; sv.y = shv[q * 4 + 1];
        sv.z = shv[q * 4 + 2]; sv.w = shv[q * 4 + 3];
        *(float4*)&shbuf[(size_t)e * 16 + q * 4] = sv;   // edge order (epilogue)
        *(float4*)&shc[(size_t)ip * 16 + q * 4] = sv;    // CSR order (aggregation)
        const float PI = 3.14159265358979f;
        float th = PI * u;
        float tc = 2.0f * cosf(th);
        float* rp = &rb_s[r * 132 + 32 * q];
        int n0 = 32 * q + 1;
#pragma unroll
        for (int g = 0; g < 2; g++) {
            int nb = n0 + 16 * g;
            float sm1 = sinf(th * (float)nb);
            float s0 = sinf(th * (float)(nb + 1));
            rp[16 * g + 0] = pref * sm1;
            rp[16 * g + 1] = pref * s0;
#pragma unroll
            for (int j = 2; j < 16; j++) {
                float s = tc * s0 - sm1;
                sm1 = s0; s0 = s;
                rp[16 * g + j] = pref * s;
            }
        }
    }
    __syncthreads();
    // ---- Phase B: 64x64 GEMM, K=128; 4 rows x 4 cols per thread
    int col0 = (tid & 15) * 4;
    int r0b = (tid >> 4) * 4;
    float4 hkeep[4];
    {
        float acc[4][4];
#pragma unroll
        for (int i = 0; i < 4; i++) { acc[i][0] = 0.f; acc[i][1] = 0.f; acc[i][2] = 0.f; acc[i][3] = 0.f; }
#pragma unroll 2
        for (int k0 = 0; k0 < NBAS; k0 += 4) {
            float4 w0 = *(float4*)&w_s[(k0 + 0) * HH + col0];
            float4 w1 = *(float4*)&w_s[(k0 + 1) * HH + col0];
            float4 w2 = *(float4*)&w_s[(k0 + 2) * HH + col0];
            float4 w3 = *(float4*)&w_s[(k0 + 3) * HH + col0];
#pragma unroll
            for (int i = 0; i < 4; i++) {
                float4 rv = *(float4*)&rb_s[(r0b + i) * 132 + k0];
                acc[i][0] += rv.x * w0.x; acc[i][1] += rv.x * w0.y; acc[i][2] += rv.x * w0.z; acc[i][3] += rv.x * w0.w;
                acc[i][0] += rv.y * w1.x; acc[i][1] += rv.y * w1.y; acc[i][2] += rv.y * w1.z; acc[i][3] += rv.y * w1.w;
                acc[i][0] += rv.z * w2.x; acc[i][1] += rv.z * w2.y; acc[i][2] += rv.z * w2.z; acc[i][3] += rv.z * w2.w;
                acc[i][0] += rv.w * w3.x; acc[i][1] += rv.w * w3.y; acc[i][2] += rv.w * w3.z; acc[i][3] += rv.w * w3.w;
            }
        }
        float4 bv = *(const float4*)&rb1[col0];
#pragma unroll
        for (int i = 0; i < 4; i++) {
            float a0 = acc[i][0] + bv.x, a1 = acc[i][1] + bv.y;
            float a2 = acc[i][2] + bv.z, a3 = acc[i][3] + bv.w;
            float4 hres;
            hres.x = a0 * sigmoidf_(a0); hres.y = a1 * sigmoidf_(a1);
            hres.z = a2 * sigmoidf_(a2); hres.w = a3 * sigmoidf_(a3);
            *(float4*)&hbuf[(size_t)(ebase + r0b + i) * HH + col0] = hres;
            hkeep[i] = hres;
        }
    }
    __syncthreads();   // rb_s fully read -> safe to overlay h_s
#pragma unroll
    for (int i = 0; i < 4; i++)
        *(float4*)&h_s[(r0b + i) * 68 + col0] = hkeep[i];
    // ---- Phase C: 3 output panels, scattered bf16 rows
    int ob = (tid & 31) << 2;
    int r0 = (tid >> 5) << 3;
#pragma unroll 1
    for (int p = 0; p < 3; p++) {
        __syncthreads();   // h_s writes done (p=0) / prev panel reads done
        for (int i = tid; i < HH * 32; i += 256) {
            int j = i >> 5, o4 = (i & 31) << 2;
            *(float4*)&w_s[j * 128 + o4] = *(const float4*)&rw2[(size_t)j * 384 + p * 128 + o4];
        }
        __syncthreads();
        float acc[8][4];
#pragma unroll
        for (int i = 0; i < 8; i++) { acc[i][0] = 0.f; acc[i][1] = 0.f; acc[i][2] = 0.f; acc[i][3] = 0.f; }
#pragma unroll 2
        for (int k0 = 0; k0 < HH; k0 += 4) {
            float4 w0 = *(float4*)&w_s[(k0 + 0) * 128 + ob];
            float4 w1 = *(float4*)&w_s[(k0 + 1) * 128 + ob];
            float4 w2 = *(float4*)&w_s[(k0 + 2) * 128 + ob];
            float4 w3 = *(float4*)&w_s[(k0 + 3) * 128 + ob];
#pragma unroll
            for (int i = 0; i < 8; i++) {
                float4 hv = *(float4*)&h_s[(r0 + i) * 68 + k0];
                acc[i][0] += hv.x * w0.x; acc[i][1] += hv.x * w0.y; acc[i][2] += hv.x * w0.z; acc[i][3] += hv.x * w0.w;
                acc[i][0] += hv.y * w1.x; acc[i][1] += hv.y * w1.y; acc[i][2] += hv.y * w1.z; acc[i][3] += hv.y * w1.w;
                acc[i][0] += hv.z * w2.x; acc[i][1] += hv.z * w2.y; acc[i][2] += hv.z * w2.z; acc[i][3] += hv.z * w2.w;
                acc[i][0] += hv.w * w3.x; acc[i][1] += hv.w * w3.y; acc[i][2] += hv.w * w3.z; acc[i][3] += hv.w * w3.w;
            }
        }
        float4 bv = *(const float4*)&rb2[p * 128 + ob];
        unsigned short* awp = awh + (size_t)p * EE * 128;
#pragma unroll
        for (int i = 0; i < 8; i++) {
            int ip = ip_s[r0 + i];
            ushort4 st;
            st.x = f2bf(acc[i][0] + bv.x);
            st.y = f2bf(acc[i][1] + bv.y);
            st.z = f2bf(acc[i][2] + bv.z);
            st.w = f2bf(acc[i][3] + bv.w);
            *(ushort4*)&awp[(size_t)ip * 128 + ob] = st;   // 8B store, half-wave = 256B row
        }
    }
}

// ---------------------------------------------------------------------------
// K2: fused per-node aggregation + node update. All big streams sequential:
// awh (bf16, 256 B/edge), shc (64 B/edge), srcc (4 B/edge); f0prev L2-resident.
template<int INIT, int FINAL>
__global__ __launch_bounds__(256) void k_aggnode(
    const unsigned short* __restrict__ awh, const float* __restrict__ shc,
    const int* __restrict__ srcc,
    const float* __restrict__ f0prev, const float* __restrict__ f_cur,
    const int* __restrict__ rowptr,
    const float* __restrict__ self_w, const float* __restrict__ msg_w,
    const float* __restrict__ gate_w,
    float* __restrict__ f_next, float* __restrict__ f0_out, int t) {
    __shared__ float agg_s[4][CC * 17];
    __shared__ float new_s[4][CC * 17];
    __shared__ float gate_s[4][CC];
    int w = threadIdx.x >> 6, lane = threadIdx.x & 63;
    int n = blockIdx.x * 4 + w;
    int c = lane & 31;
    int half = lane >> 5;
    float acc0[3] = {0.f, 0.f, 0.f};
    float acc1[7] = {0.f, 0.f, 0.f, 0.f, 0.f, 0.f, 0.f};
    int beg = rowptr[n], end = rowptr[n + 1];
    for (int k = beg; k < end; k++) {
        int src = srcc[k];
        float fs = f0prev[src * CC + c];
        float a0 = bf2f(awh[(size_t)k * 128 + lane]) * fs;
        float a1 = bf2f(awh[(size_t)k * 128 + 64 + lane]) * fs;
        const float4* shp = (const float4*)(shc + (size_t)k * 16);
        float4 s0 = shp[0], s1 = shp[1], s2 = shp[2], s3 = shp[3];
        if (half == 0) {
            acc0[0] += a0 * s0.x;                                          // l=0
            acc1[0] += a1 * s1.x; acc1[1] += a1 * s1.y;                    // l=2
            acc1[2] += a1 * s1.z; acc1[3] += a1 * s1.w; acc1[4] += a1 * s2.x;
        } else {
            acc0[0] += a0 * s0.y; acc0[1] += a0 * s0.z; acc0[2] += a0 * s0.w;   // l=1
            acc1[0] += a1 * s2.y; acc1[1] += a1 * s2.z; acc1[2] += a1 * s2.w;   // l=3
            acc1[3] += a1 * s3.x; acc1[4] += a1 * s3.y; acc1[5] += a1 * s3.z; acc1[6] += a1 * s3.w;
        }
    }
    {
        int l0 = half, dl0 = 2 * l0 + 1, mo0 = l0 * l0;
        int l1 = 2 + half, dl1 = 2 * l1 + 1, mo1 = l1 * l1;
        float* ap = &agg_s[w][c * 17];
#pragma unroll
        for (int m = 0; m < 3; m++)
            if (m < dl0) ap[mo0 + m] = acc0[m];
#pragma unroll
        for (int m = 0; m < 7; m++)
            if (m < dl1) ap[mo1 + m] = acc1[m];
    }
    int d = c, mg = half;
#pragma unroll
    for (int k = 0; k < 8; k++) {
        int m = mg + 2 * k;
        int l = (m == 0) ? 0 : (m < 4) ? 1 : (m < 9) ? 2 : 3;
        const float* sw = self_w + (size_t)((t * 4 + l) * CC) * CC + d;
        const float* mw = msg_w + (size_t)((t * 4 + l) * CC) * CC + d;
        float acc = 0.0f;
#pragma unroll 8
        for (int c2 = 0; c2 < CC; c2++) {
            float fv;
            if (INIT) fv = (m == 0) ? f0prev[n * CC + c2] : 0.0f;
            else fv = f_cur[((size_t)n * CC + c2) * 16 + m];
            acc += fv * sw[c2 * CC] + agg_s[w][c2 * 17 + m] * mw[c2 * CC];
        }
        new_s[w][d * 17 + m] = acc;
    }
    if (mg == 0) {
        float g = 0.0f;
#pragma unroll 8
        for (int c2 = 0; c2 < CC; c2++)
            g += new_s[w][c2 * 17 + 0] * gate_w[((size_t)t * CC + c2) * CC + d];
        gate_s[w][d] = sigmoidf_(g);
    }
#pragma unroll
    for (int k = 0; k < 8; k++) {
        int m = mg + 2 * k;
        float v = new_s[w][d * 17 + m];
        if (m == 0) v = v * sigmoidf_(v);
        else v *= gate_s[w][d];
        if (FINAL) {
            int l = (m == 0) ? 0 : (m < 4) ? 1 : (m < 9) ? 2 : 3;
            f_next[(size_t)n * 512 + 32 * l * l + d * (2 * l + 1) + (m - l * l)] = v;
        } else {
            f_next[((size_t)n * CC + d) * 16 + m] = v;
        }
        if (m == 0) f0_out[n * CC + d] = v;
    }
}

// ---------------------------------------------------------------------------
template<int DL>
__device__ __forceinline__ void emit_edge(float* outp, const float* shp,
                                          float e0, float e1, float e2, float e3) {
    float ew[4] = {e0, e1, e2, e3};
    float buf[4 * DL];
#pragma unroll
    for (int cc = 0; cc < 4; cc++)
#pragma unroll
        for (int m = 0; m < DL; m++) buf[cc * DL + m] = ew[cc] * shp[m];
#pragma unroll
    for (int t = 0; t < DL; t++) *(float4*)&outp[t * 4] = *(float4*)&buf[t * 4];
}

// ---------------------------------------------------------------------------
// K3: edge-output GEMM + sh expansion (fused, no intermediate)
__global__ __launch_bounds__(256) void k_edge_out(
    const float* __restrict__ hbuf, const float* __restrict__ shbuf,
    const float* __restrict__ edge_w, const float* __restrict__ edge_b,
    const float* __restrict__ f0, const int* __restrict__ ei,
    float* __restrict__ out) {
    __shared__ float w_s[HH * 128];      // 32 KB
    __shared__ float h_s[64][68];        // 17 KB
    __shared__ float sh_s[64][16];       // 4 KB
    int tid = threadIdx.x;
    int ebase = blockIdx.x * 64;
    for (int i = tid; i < HH * 32; i += 256) {
        int j = i >> 5, o4 = (i & 31) << 2;
        *(float4*)&w_s[j * 128 + o4] = *(const float4*)&edge_w[(size_t)j * 128 + o4];
    }
    {
        int r = tid >> 2, q = tid & 3;
        int e = ebase + r;
        const float4* hp = (const float4*)(hbuf + (size_t)e * HH + q * 16);
        float4 v0 = hp[0], v1 = hp[1], v2 = hp[2], v3 = hp[3];
        float4* dp = (float4*)&h_s[r][q * 16];
        dp[0] = v0; dp[1] = v1; dp[2] = v2; dp[3] = v3;
        *(float4*)&sh_s[r][q * 4] = *(const float4*)&shbuf[(size_t)e * 16 + q * 4];
    }
    __syncthreads();
    int ob = (tid & 31) << 2;
    int r0 = (tid >> 5) << 3;
    float acc[8][4];
#pragma unroll
    for (int i = 0; i < 8; i++) { acc[i][0] = 0.f; acc[i][1] = 0.f; acc[i][2] = 0.f; acc[i][3] = 0.f; }
#pragma unroll 2
    for (int k0 = 0; k0 < HH; k0 += 4) {
        float4 w0 = *(float4*)&w_s[(k0 + 0) * 128 + ob];
        float4 w1 = *(float4*)&w_s[(k0 + 1) * 128 + ob];
        float4 w2 = *(float4*)&w_s[(k0 + 2) * 128 + ob];
        float4 w3 = *(float4*)&w_s[(k0 + 3) * 128 + ob];
#pragma unroll
        for (int i = 0; i < 8; i++) {
            float4 hv = *(float4*)&h_s[r0 + i][k0];
            acc[i][0] += hv.x * w0.x; acc[i][1] += hv.x * w0.y; acc[i][2] += hv.x * w0.z; acc[i][3] += hv.x * w0.w;
            acc[i][0] += hv.y * w1.x; acc[i][1] += hv.y * w1.y; acc[i][2] += hv.y * w1.z; acc[i][3] += hv.y * w1.w;
            acc[i][0] += hv.z * w2.x; acc[i][1] += hv.z * w2.y; acc[i][2] += hv.z * w2.z; acc[i][3] += hv.z * w2.w;
            acc[i][0] += hv.w * w3.x; acc[i][1] += hv.w * w3.y; acc[i][2] += hv.w * w3.z; acc[i][3] += hv.w * w3.w;
        }
    }
    float4 bv = *(const float4*)&edge_b[ob];
    int l = ob >> 5;
    int cbase = ob & 31;
    int dl = 2 * l + 1, mo = l * l, co = 32 * l * l;
#pragma unroll
    for (int i = 0; i < 8; i++) {
        int rr = r0 + i;
        int e = ebase + rr;
        int src = ei[e], dst = ei[EE + e];
        float4 g1 = *(const float4*)&f0[src * CC + cbase];
        float4 g2 = *(const float4*)&f0[dst * CC + cbase];
        float e0 = (acc[i][0] + bv.x) * (g1.x + g2.x);
        float e1 = (acc[i][1] + bv.y) * (g1.y + g2.y);
        float e2 = (acc[i][2] + bv.z) * (g1.z + g2.z);
        float e3 = (acc[i][3] + bv.w) * (g1.w + g2.w);
        float* outp = out + ((size_t)NN + e) * 512 + co + (size_t)cbase * dl;
        const float* shp = &sh_s[rr][mo];
        if (l == 0)      emit_edge<1>(outp, shp, e0, e1, e2, e3);
        else if (l == 1) emit_edge<3>(outp, shp, e0, e1, e2, e3);
        else if (l == 2) emit_edge<5>(outp, shp, e0, e1, e2, e3);
        else             emit_edge<7>(outp, shp, e0, e1, e2, e3);
    }
}

// ---------------------------------------------------------------------------
extern "C" void kernel_launch(void* const* d_in, const int* in_sizes, int n_in,
                              void* d_out, int out_size, void* d_ws, size_t ws_size,
                              hipStream_t stream) {
    const float* pos        = (const float*)d_in[0];
    const float* node_embed = (const float*)d_in[1];
    const float* rw1        = (const float*)d_in[2];
    const float* rb1        = (const float*)d_in[3];
    const float* rw2        = (const float*)d_in[4];
    const float* rb2        = (const float*)d_in[5];
    const float* self_w     = (const float*)d_in[6];
    const float* msg_w      = (const float*)d_in[7];
    const float* gate_w     = (const float*)d_in[8];
    const float* edge_w     = (const float*)d_in[9];
    const float* edge_b     = (const float*)d_in[10];
    const int* species      = (const int*)d_in[11];
    const int* ei           = (const int*)d_in[12];
    float* out = (float*)d_out;

    // --- workspace layout (base ~88 MB always in ws) ---
    float* f0fin = (float*)d_ws;
    float* f0A   = f0fin + (size_t)NN * CC;
    float* f0B   = f0A + (size_t)NN * CC;
    float* hbuf  = f0B + (size_t)NN * CC;
    float* shbuf = hbuf + (size_t)EE * HH;
    float* shc   = shbuf + (size_t)EE * 16;
    float* fA    = shc + (size_t)EE * 16;
    int* deg     = (int*)(fA + (size_t)NN * 512);
    int* rowptr  = deg + NN;                     // NN+1 used, pad to NN+2 for 8B align
    int* cursor  = rowptr + NN + 2;
    int* ipos    = cursor + NN;
    int* srcc    = ipos + EE;
    char* endbase = (char*)(srcc + EE);
    size_t base_need = (size_t)(endbase - (char*)d_ws);
    size_t extra_need = (size_t)NN * 512 * 4 + (size_t)3 * EE * 128 * 2;  // fB f32 + awh bf16
    float* fB;
    unsigned short* awh;
    if (ws_size >= base_need + extra_need) {
        fB  = (float*)endbase;
        awh = (unsigned short*)(fB + (size_t)NN * 512);
    } else {
        // fB (20.5 MB) + awh (123 MB) in the 327.7 MB out edge region;
        // both dead before k_edge_out writes it.
        fB  = out + (size_t)NN * 512;
        awh = (unsigned short*)(fB + (size_t)NN * 512);
    }

    // CSR build
    hipMemsetAsync(deg, 0, (size_t)NN * 4, stream);
    hipMemsetAsync(cursor, 0, (size_t)NN * 4, stream);
    k_deg<<<(EE + 255) / 256, 256, 0, stream>>>(ei, deg);
    k_scan<<<1, 256, 0, stream>>>(deg, rowptr);
    k_scatter<<<(EE + 255) / 256, 256, 0, stream>>>(ei, rowptr, cursor, ipos, srcc);

    k_init_f0<<<(NN * CC + 255) / 256, 256, 0, stream>>>(node_embed, species, f0A);
    k_edge_pre<<<EE / 64, 256, 0, stream>>>(pos, rw1, rb1, rw2, rb2, ei, ipos,
                                            hbuf, shbuf, shc, awh);

    k_aggnode<1, 0><<<NN / 4, 256, 0, stream>>>(awh, shc, srcc, f0A, nullptr,
        rowptr, self_w, msg_w, gate_w, fA, f0B, 0);
    k_aggnode<0, 0><<<NN / 4, 256, 0, stream>>>(awh + (size_t)EE * 128, shc, srcc, f0B, fA,
        rowptr, self_w, msg_w, gate_w, fB, f0A, 1);
    k_aggnode<0, 1><<<NN / 4, 256, 0, stream>>>(awh + (size_t)2 * EE * 128, shc, srcc, f0A, fB,
        rowptr, self_w, msg_w, gate_w, out, f0fin, 2);

    k_edge_out<<<EE / 64, 256, 0, stream>>>(hbuf, shbuf, edge_w, edge_b, f0fin, ei, out);
}